// Round 1
// baseline (307.512 us; speedup 1.0000x reference)
//
#include <hip/hip_runtime.h>
#include <math.h>

// ---------------------------------------------------------------------------
// Kernel 1: precompute emb_conv = emb_table @ conv_w, emb_cross = emb_table @ cross_w
// emb_table: [nrows,128], conv_w/cross_w: [128,10] -> out [nrows,10] each.
// Block = 256 threads handles 16 rows; weights + rows staged in LDS.
// ---------------------------------------------------------------------------
__global__ __launch_bounds__(256) void precompute_proj(
    const float* __restrict__ emb,
    const float* __restrict__ conv_w,
    const float* __restrict__ cross_w,
    float* __restrict__ out_conv,
    float* __restrict__ out_cross,
    int nrows)
{
    __shared__ float s_w[128 * 20];    // [k][j]: j<10 conv, j>=10 cross
    __shared__ float s_rows[16 * 128];

    const int tid = threadIdx.x;
    for (int i = tid; i < 1280; i += 256) {
        int k = i / 10, j = i % 10;
        s_w[k * 20 + j]      = conv_w[i];
        s_w[k * 20 + 10 + j] = cross_w[i];
    }
    const int row0 = blockIdx.x * 16;
    for (int i = tid; i < 16 * 128; i += 256) {
        int r = row0 + i / 128;
        s_rows[i] = (r < nrows) ? emb[(size_t)r * 128 + (i % 128)] : 0.0f;
    }
    __syncthreads();

    for (int w = tid; w < 16 * 20; w += 256) {
        int lr = w / 20, j = w % 20;
        int r = row0 + lr;
        if (r >= nrows) continue;
        const float* rowp = &s_rows[lr * 128];
        float acc = 0.0f;
#pragma unroll
        for (int k = 0; k < 128; ++k) acc += rowp[k] * s_w[k * 20 + j];
        if (j < 10) out_conv[(size_t)r * 10 + j] = acc;
        else        out_cross[(size_t)r * 10 + (j - 10)] = acc;
    }
}

// ---------------------------------------------------------------------------
// Kernel 2: fully fused per-sample forward. One block (256 thr) per sample.
// ---------------------------------------------------------------------------
__global__ __launch_bounds__(256) void gmn_fused(
    const int* __restrict__ tok_u_all, const int* __restrict__ tok_r_all,
    const int* __restrict__ adj_u_all, const int* __restrict__ adj_r_all,
    const float* __restrict__ emb_conv, const float* __restrict__ emb_cross,
    const float* __restrict__ conv_b,
    const float* __restrict__ attn,
    const float* __restrict__ assign_w,
    const float* __restrict__ mp_w1, const float* __restrict__ mp_b1,
    const float* __restrict__ mp_w2, const float* __restrict__ mp_b2,
    const float* __restrict__ ffn_w1, const float* __restrict__ ffn_b1,
    const float* __restrict__ ffn_w2, const float* __restrict__ ffn_b2,
    float* __restrict__ out, int E)
{
    const int b   = blockIdx.x;
    const int tid = threadIdx.x;

    const int* tok_u = tok_u_all + (size_t)b * 50;
    const int* tok_r = tok_r_all + (size_t)b * 50;
    const int* adj_u = adj_u_all + (size_t)b * 2 * E;
    const int* adj_r = adj_r_all + (size_t)b * 2 * E;

    __shared__ float s_attn[2500];
    __shared__ float s_xw[2][500];     // emb_conv gathers (GCN xw)
    __shared__ float s_ci[2][500];     // emb_cross gathers
    __shared__ float s_self[2][500];   // GCN outputs (incl bias)
    __shared__ float s_cross[2][500];  // attn @ ci[other]
    __shared__ float s_dinv[2][50];    // deg -> rsqrt(deg)
    __shared__ float s_dist[2][50];
    __shared__ float s_h1[2][1000];    // [50,20]
    __shared__ float s_h2[2][1000];
    __shared__ int   s_tok[2][50];
    __shared__ float s_g[2][20];
    __shared__ float s_feat[80];
    __shared__ float s_t1[40];

    // phase 0: attn stage, tokens, deg init (self-loop = 1)
    for (int i = tid; i < 2500; i += 256) s_attn[i] = attn[i];
    if (tid < 50) { s_tok[0][tid] = tok_u[tid]; s_tok[1][tid] = tok_r[tid]; }
    if (tid < 100) s_dinv[tid / 50][tid % 50] = 1.0f;
    __syncthreads();

    // phase 1: gather projected rows; accumulate in-degree
    for (int i = tid; i < 1000; i += 256) {
        int g = i / 500, idx = i % 500;
        int row = idx / 10, j = idx % 10;
        int t = s_tok[g][row];
        s_xw[g][idx] = emb_conv[(size_t)t * 10 + j];
        s_ci[g][idx] = emb_cross[(size_t)t * 10 + j];
    }
    for (int e = tid; e < 2 * E; e += 256) {
        int g = e / E, ei = e % E;
        const int* adj = (g == 0) ? adj_u : adj_r;
        int dst = adj[E + ei];
        atomicAdd(&s_dinv[g][dst], 1.0f);
    }
    __syncthreads();

    // phase 2: dinv = rsqrt(deg)  (deg >= 1 always due to self-loops)
    if (tid < 100) {
        int g = tid / 50, i = tid % 50;
        s_dinv[g][i] = rsqrtf(s_dinv[g][i]);
    }
    __syncthreads();

    // phase 3: self-loop contribution + bias (bias added exactly once here)
    for (int i = tid; i < 1000; i += 256) {
        int g = i / 500, idx = i % 500;
        int row = idx / 10, j = idx % 10;
        float d = s_dinv[g][row];
        s_self[g][idx] = d * d * s_xw[g][idx] + conv_b[j];
    }
    __syncthreads();

    // phase 4: edge aggregation (LDS atomics) + cross = attn @ ci[other]
    for (int w = tid; w < 2 * E * 10; w += 256) {
        int g = w / (E * 10);
        int rem = w % (E * 10);
        int ei = rem / 10, j = rem % 10;
        const int* adj = (g == 0) ? adj_u : adj_r;
        int src = adj[ei], dst = adj[E + ei];
        float nrm = s_dinv[g][src] * s_dinv[g][dst];
        atomicAdd(&s_self[g][dst * 10 + j], nrm * s_xw[g][src * 10 + j]);
    }
    for (int w = tid; w < 1000; w += 256) {
        int g = w / 500, idx = w % 500;
        int i = idx / 10, j = idx % 10;
        const float* ci = s_ci[g ^ 1];   // u_cross uses r's projection & vice versa
        float acc = 0.0f;
#pragma unroll
        for (int k = 0; k < 50; ++k) acc += s_attn[i * 50 + k] * ci[k * 10 + j];
        s_cross[g][idx] = acc;
    }
    __syncthreads();

    // phase 5: cosine distance per row
    if (tid < 100) {
        int g = tid / 50, r = tid % 50;
        float dot = 0.0f, na2 = 0.0f, nc2 = 0.0f;
#pragma unroll
        for (int j = 0; j < 10; ++j) {
            float aw = assign_w[r * 10 + j];
            float a = aw * s_self[g][r * 10 + j];
            float c = aw * s_cross[g][r * 10 + j];
            dot += a * c; na2 += a * a; nc2 += c * c;
        }
        float na = fmaxf(sqrtf(na2), 1e-8f);
        float nc = fmaxf(sqrtf(nc2), 1e-8f);
        s_dist[g][r] = dot / (na * nc);
    }
    __syncthreads();

    // phase 6: h1 = relu([dist, self] @ w1 + b1)   -> [2][50][20]
    for (int w = tid; w < 2000; w += 256) {
        int g = w / 1000, idx = w % 1000;
        int r = idx / 20, o = idx % 20;
        float acc = mp_b1[o] + s_dist[g][r] * mp_w1[o];  // w1[0][o]
#pragma unroll
        for (int j = 0; j < 10; ++j)
            acc += s_self[g][r * 10 + j] * mp_w1[(1 + j) * 20 + o];
        s_h1[g][idx] = fmaxf(acc, 0.0f);
    }
    __syncthreads();

    // phase 7: h2 = h1 @ w2 + b2
    for (int w = tid; w < 2000; w += 256) {
        int g = w / 1000, idx = w % 1000;
        int r = idx / 20, o = idx % 20;
        float acc = mp_b2[o];
#pragma unroll
        for (int t = 0; t < 20; ++t)
            acc += s_h1[g][r * 20 + t] * mp_w2[t * 20 + o];
        s_h2[g][idx] = acc;
    }
    __syncthreads();

    // phase 8: g = max over rows
    if (tid < 40) {
        int g = tid / 20, o = tid % 20;
        float m = -INFINITY;
        for (int r = 0; r < 50; ++r) m = fmaxf(m, s_h2[g][r * 20 + o]);
        s_g[g][o] = m;
    }
    __syncthreads();

    // phase 9: feature vector [g_u, g_r, g_u*g_r, |g_u-g_r|]
    if (tid < 80) {
        float f;
        if (tid < 20)      f = s_g[0][tid];
        else if (tid < 40) f = s_g[1][tid - 20];
        else if (tid < 60) f = s_g[0][tid - 40] * s_g[1][tid - 40];
        else               f = fabsf(s_g[0][tid - 60] - s_g[1][tid - 60]);
        s_feat[tid] = f;
    }
    __syncthreads();

    // phase 10: FFN layer 1 (80 -> 40) with relu
    if (tid < 40) {
        float acc = ffn_b1[tid];
#pragma unroll
        for (int i = 0; i < 80; ++i) acc += s_feat[i] * ffn_w1[i * 40 + tid];
        s_t1[tid] = fmaxf(acc, 0.0f);
    }
    __syncthreads();

    // phase 11: FFN layer 2 (40 -> 1) + sigmoid
    if (tid == 0) {
        float acc = ffn_b2[0];
#pragma unroll
        for (int o = 0; o < 40; ++o) acc += s_t1[o] * ffn_w2[o];
        out[b] = 1.0f / (1.0f + expf(-acc));
    }
}

extern "C" void kernel_launch(void* const* d_in, const int* in_sizes, int n_in,
                              void* d_out, int out_size, void* d_ws, size_t ws_size,
                              hipStream_t stream)
{
    const int*   tok_u    = (const int*)d_in[0];
    const int*   tok_r    = (const int*)d_in[1];
    const int*   adj_u    = (const int*)d_in[2];
    const int*   adj_r    = (const int*)d_in[3];
    const float* emb      = (const float*)d_in[4];
    const float* conv_w   = (const float*)d_in[5];
    const float* conv_b   = (const float*)d_in[6];
    const float* cross_w  = (const float*)d_in[7];
    const float* attn     = (const float*)d_in[8];
    const float* assign_w = (const float*)d_in[9];
    const float* mp_w1    = (const float*)d_in[10];
    const float* mp_b1    = (const float*)d_in[11];
    const float* mp_w2    = (const float*)d_in[12];
    const float* mp_b2    = (const float*)d_in[13];
    const float* ffn_w1   = (const float*)d_in[14];
    const float* ffn_b1   = (const float*)d_in[15];
    const float* ffn_w2   = (const float*)d_in[16];
    const float* ffn_b2   = (const float*)d_in[17];

    const int B     = in_sizes[0] / 50;
    const int E     = in_sizes[2] / (2 * B);
    const int nrows = in_sizes[4] / 128;

    float* emb_conv  = (float*)d_ws;
    float* emb_cross = emb_conv + (size_t)nrows * 10;

    precompute_proj<<<(nrows + 15) / 16, 256, 0, stream>>>(
        emb, conv_w, cross_w, emb_conv, emb_cross, nrows);

    gmn_fused<<<B, 256, 0, stream>>>(
        tok_u, tok_r, adj_u, adj_r, emb_conv, emb_cross, conv_b,
        attn, assign_w, mp_w1, mp_b1, mp_w2, mp_b2,
        ffn_w1, ffn_b1, ffn_w2, ffn_b2,
        (float*)d_out, E);
}

// Round 2
// 300.726 us; speedup vs baseline: 1.0226x; 1.0226x over previous
//
#include <hip/hip_runtime.h>
#include <math.h>

#define NN 50
#define EMAX 256

// ---------------------------------------------------------------------------
// Kernel 1: emb_proj[r][j] = (j<10) ? emb[r]@conv_w[:,j] : emb[r]@cross_w[:,j-10]
// One thread per row; row held in registers; weights staged in LDS.
// ---------------------------------------------------------------------------
__global__ __launch_bounds__(256) void precompute_proj(
    const float* __restrict__ emb,
    const float* __restrict__ conv_w,
    const float* __restrict__ cross_w,
    float* __restrict__ emb_proj,
    int nrows)
{
    __shared__ float s_w[128 * 20];   // [k][j]: j<10 conv, j>=10 cross
    const int tid = threadIdx.x;
    for (int i = tid; i < 1280; i += 256) {
        int k = i / 10, j = i % 10;
        s_w[k * 20 + j]      = conv_w[i];
        s_w[k * 20 + 10 + j] = cross_w[i];
    }
    __syncthreads();

    const int r = blockIdx.x * 256 + tid;
    if (r >= nrows) return;

    float row[128];
    const float4* rp = (const float4*)(emb + (size_t)r * 128);
#pragma unroll
    for (int q = 0; q < 32; ++q) {
        float4 v = rp[q];
        row[q * 4 + 0] = v.x; row[q * 4 + 1] = v.y;
        row[q * 4 + 2] = v.z; row[q * 4 + 3] = v.w;
    }
    float acc[20];
#pragma unroll
    for (int j = 0; j < 20; ++j) acc[j] = 0.0f;
#pragma unroll
    for (int k = 0; k < 128; ++k) {
        float x = row[k];
#pragma unroll
        for (int j = 0; j < 20; ++j) acc[j] += x * s_w[k * 20 + j];
    }
    float4* op = (float4*)(emb_proj + (size_t)r * 20);
#pragma unroll
    for (int q = 0; q < 5; ++q)
        op[q] = make_float4(acc[q * 4], acc[q * 4 + 1], acc[q * 4 + 2], acc[q * 4 + 3]);
}

// ---------------------------------------------------------------------------
// Kernel 2: fused per-sample forward. One block (256 thr) per sample.
// LDS ~31.9 KB -> 5 blocks/CU.
// ---------------------------------------------------------------------------
__global__ __launch_bounds__(256) void gmn_fused(
    const int* __restrict__ tok_u_all, const int* __restrict__ tok_r_all,
    const int* __restrict__ adj_u_all, const int* __restrict__ adj_r_all,
    const float* __restrict__ emb_proj,
    const float* __restrict__ conv_b,
    const float* __restrict__ attn,
    const float* __restrict__ assign_w,
    const float* __restrict__ mp_w1, const float* __restrict__ mp_b1,
    const float* __restrict__ mp_w2, const float* __restrict__ mp_b2,
    const float* __restrict__ ffn_w1, const float* __restrict__ ffn_b1,
    const float* __restrict__ ffn_w2, const float* __restrict__ ffn_b2,
    float* __restrict__ out, int E)
{
    const int b   = blockIdx.x;
    const int tid = threadIdx.x;

    __shared__ float s_attn[2500];      // attn; reused as max-scratch at the end
    __shared__ float s_proj[2][1000];   // [row][20] = xw(0..9)|ci(10..19); later h1
    __shared__ float s_sc[2][1000];     // [row][20] = self(0..9)|cross(10..19); later h2
    __shared__ int   s_adj[2][2 * EMAX];
    __shared__ int   s_tok[2][NN];
    __shared__ float s_dinv[2][NN];
    __shared__ float s_dist[2][NN];
    __shared__ float s_g[2][20];
    __shared__ float s_t1[40];

    // ---- phase 0: stage adj (int4), attn (float4), tokens; init dinv & bias
    {
        const int* au = adj_u_all + (size_t)b * 2 * E;
        const int* ar = adj_r_all + (size_t)b * 2 * E;
        if ((E & 3) == 0) {
            const int n4 = 2 * E / 4;
            const int4* au4 = (const int4*)au;
            const int4* ar4 = (const int4*)ar;
            for (int i = tid; i < 2 * n4; i += 256) {
                int g = i / n4, k = i % n4;
                ((int4*)s_adj[g])[k] = g ? ar4[k] : au4[k];
            }
        } else {
            for (int i = tid; i < 2 * 2 * E; i += 256) {
                int g = i / (2 * E), k = i % (2 * E);
                s_adj[g][k] = g ? ar[k] : au[k];
            }
        }
        const float4* at4 = (const float4*)attn;
        for (int i = tid; i < 625; i += 256) ((float4*)s_attn)[i] = at4[i];
        if (tid < 100) {
            int g = tid / 50, r = tid % 50;
            s_tok[g][r]  = g ? tok_r_all[(size_t)b * 50 + r] : tok_u_all[(size_t)b * 50 + r];
            s_dinv[g][r] = 1.0f;   // self-loop degree
        }
        for (int i = tid; i < 1000; i += 256) {
            int g = i / 500, rem = i % 500, row = rem / 10, j = rem % 10;
            s_sc[g][row * 20 + j] = conv_b[j];   // bias init; edges accumulate on top
        }
    }
    __syncthreads();

    // ---- phase 1: gather projected rows (float4) + in-degree atomics
    for (int i = tid; i < 500; i += 256) {
        int g = i / 250, rem = i % 250, row = rem / 5, q = rem % 5;
        int t = s_tok[g][row];
        float4 v = *(const float4*)(emb_proj + (size_t)t * 20 + q * 4);
        *(float4*)&s_proj[g][row * 20 + q * 4] = v;
    }
    for (int e = tid; e < 2 * E; e += 256) {
        int g = e / E, ei = e % E;
        atomicAdd(&s_dinv[g][s_adj[g][E + ei]], 1.0f);
    }
    __syncthreads();

    // ---- phase 2: dinv = rsqrt(deg)
    if (tid < 100) {
        int g = tid / 50, r = tid % 50;
        s_dinv[g][r] = rsqrtf(s_dinv[g][r]);
    }
    __syncthreads();

    // ---- phase 3: edge aggregation (incl. self-loop virtual edges) + cross matmul
    {
        const int EV = E + NN;   // E real edges + 50 self loops per graph
        for (int e = tid; e < 2 * EV; e += 256) {
            int g = e / EV, ei = e % EV;
            int src, dst;
            if (ei < E) { src = s_adj[g][ei]; dst = s_adj[g][E + ei]; }
            else        { src = dst = ei - E; }
            float nrm = s_dinv[g][src] * s_dinv[g][dst];
#pragma unroll
            for (int j = 0; j < 10; ++j)
                atomicAdd(&s_sc[g][dst * 20 + j], nrm * s_proj[g][src * 20 + j]);
        }
        for (int w = tid; w < 1000; w += 256) {
            int g = w / 500, rem = w % 500, i = rem / 10, j = rem % 10;
            const float* ci = s_proj[g ^ 1];   // cross uses the OTHER graph's proj
            float acc = 0.0f;
#pragma unroll
            for (int k = 0; k < 50; ++k)
                acc += s_attn[i * 50 + k] * ci[k * 20 + 10 + j];
            s_sc[g][i * 20 + 10 + j] = acc;
        }
    }
    __syncthreads();

    // ---- phase 4: cosine distance per row
    if (tid < 100) {
        int g = tid / 50, r = tid % 50;
        float dot = 0.0f, na2 = 0.0f, nc2 = 0.0f;
#pragma unroll
        for (int j = 0; j < 10; ++j) {
            float aw = assign_w[r * 10 + j];
            float a = aw * s_sc[g][r * 20 + j];
            float c = aw * s_sc[g][r * 20 + 10 + j];
            dot += a * c; na2 += a * a; nc2 += c * c;
        }
        float na = fmaxf(sqrtf(na2), 1e-8f);
        float nc = fmaxf(sqrtf(nc2), 1e-8f);
        s_dist[g][r] = dot / (na * nc);
    }
    __syncthreads();

    // ---- phase 5: h1 = relu([dist, self] @ w1 + b1) -> s_proj (overwrites)
    for (int w = tid; w < 2000; w += 256) {
        int g = w / 1000, rem = w % 1000, r = rem / 20, o = rem % 20;
        float acc = mp_b1[o] + s_dist[g][r] * mp_w1[o];
#pragma unroll
        for (int j = 0; j < 10; ++j)
            acc += s_sc[g][r * 20 + j] * mp_w1[(1 + j) * 20 + o];
        s_proj[g][r * 20 + o] = fmaxf(acc, 0.0f);
    }
    __syncthreads();

    // ---- phase 6: h2 = h1 @ w2 + b2 -> s_sc (overwrites)
    for (int w = tid; w < 2000; w += 256) {
        int g = w / 1000, rem = w % 1000, r = rem / 20, o = rem % 20;
        float acc = mp_b2[o];
#pragma unroll
        for (int t = 0; t < 20; ++t)
            acc += s_proj[g][r * 20 + t] * mp_w2[t * 20 + o];
        s_sc[g][r * 20 + o] = acc;
    }
    __syncthreads();

    // ---- phase 7: max over rows, two-stage (reuse s_attn as scratch)
    float* s_part = s_attn;
    if (tid < 200) {
        int g = tid / 100, rem = tid % 100, o = rem / 5, c = rem % 5;
        float m = -INFINITY;
        for (int r = c * 10; r < c * 10 + 10; ++r)
            m = fmaxf(m, s_sc[g][r * 20 + o]);
        s_part[tid] = m;
    }
    __syncthreads();
    if (tid < 40) {
        int g = tid / 20, o = tid % 20;
        float m = -INFINITY;
#pragma unroll
        for (int c = 0; c < 5; ++c)
            m = fmaxf(m, s_part[g * 100 + o * 5 + c]);
        s_g[g][o] = m;
    }
    __syncthreads();

    // ---- phase 8: FFN layer 1 (feat computed on the fly from s_g)
    if (tid < 40) {
        float acc = ffn_b1[tid];
#pragma unroll
        for (int i = 0; i < 20; ++i) {
            float gu = s_g[0][i], gr = s_g[1][i];
            acc += gu * ffn_w1[i * 40 + tid]
                 + gr * ffn_w1[(20 + i) * 40 + tid]
                 + gu * gr * ffn_w1[(40 + i) * 40 + tid]
                 + fabsf(gu - gr) * ffn_w1[(60 + i) * 40 + tid];
        }
        s_t1[tid] = fmaxf(acc, 0.0f);
    }
    __syncthreads();

    // ---- phase 9: FFN layer 2 + sigmoid
    if (tid == 0) {
        float acc = ffn_b2[0];
#pragma unroll
        for (int o = 0; o < 40; ++o) acc += s_t1[o] * ffn_w2[o];
        out[b] = 1.0f / (1.0f + expf(-acc));
    }
}

extern "C" void kernel_launch(void* const* d_in, const int* in_sizes, int n_in,
                              void* d_out, int out_size, void* d_ws, size_t ws_size,
                              hipStream_t stream)
{
    const int*   tok_u    = (const int*)d_in[0];
    const int*   tok_r    = (const int*)d_in[1];
    const int*   adj_u    = (const int*)d_in[2];
    const int*   adj_r    = (const int*)d_in[3];
    const float* emb      = (const float*)d_in[4];
    const float* conv_w   = (const float*)d_in[5];
    const float* conv_b   = (const float*)d_in[6];
    const float* cross_w  = (const float*)d_in[7];
    const float* attn     = (const float*)d_in[8];
    const float* assign_w = (const float*)d_in[9];
    const float* mp_w1    = (const float*)d_in[10];
    const float* mp_b1    = (const float*)d_in[11];
    const float* mp_w2    = (const float*)d_in[12];
    const float* mp_b2    = (const float*)d_in[13];
    const float* ffn_w1   = (const float*)d_in[14];
    const float* ffn_b1   = (const float*)d_in[15];
    const float* ffn_w2   = (const float*)d_in[16];
    const float* ffn_b2   = (const float*)d_in[17];

    const int B     = in_sizes[0] / 50;
    const int E     = in_sizes[2] / (2 * B);
    const int nrows = in_sizes[4] / 128;

    float* emb_proj = (float*)d_ws;   // [nrows][20]

    precompute_proj<<<(nrows + 255) / 256, 256, 0, stream>>>(
        emb, conv_w, cross_w, emb_proj, nrows);

    gmn_fused<<<B, 256, 0, stream>>>(
        tok_u, tok_r, adj_u, adj_r, emb_proj, conv_b,
        attn, assign_w, mp_w1, mp_b1, mp_w2, mp_b2,
        ffn_w1, ffn_b1, ffn_w2, ffn_b2,
        (float*)d_out, E);
}